// Round 1
// baseline (488.297 us; speedup 1.0000x reference)
//
#include <hip/hip_runtime.h>

#define HIDDEN 1024
#define NHEADS 16
#define DKH   64
#define BATCH 2
#define SEQ   2048
#define MTOT  (BATCH*SEQ)   // 4096

using bf16x8 = __attribute__((ext_vector_type(8))) short;
using f32x4  = __attribute__((ext_vector_type(4))) float;
using u16x4  = __attribute__((ext_vector_type(4))) unsigned short;

__device__ __forceinline__ unsigned short f2bf(float f) {
    union { float f; unsigned u; } v; v.f = f;
    return (unsigned short)((v.u + 0x7FFFu + ((v.u >> 16) & 1u)) >> 16);
}

__device__ __forceinline__ void gload16(const unsigned short* g, unsigned short* l) {
    __builtin_amdgcn_global_load_lds((const __attribute__((address_space(1))) void*)g,
                                     (__attribute__((address_space(3))) void*)l, 16, 0, 0);
}

// ---------------- converts ----------------
__global__ __launch_bounds__(256) void cvt_qkv(const float4* __restrict__ q,
                                               const float4* __restrict__ k,
                                               const float4* __restrict__ v,
                                               u16x4* __restrict__ out) {
    int i = blockIdx.x * 256 + threadIdx.x;   // grid = 3*1048576/256
    const int per = MTOT * HIDDEN / 4;        // 1048576 float4 per tensor
    const float4* src; int t;
    if (i < per)            { src = q; t = 0; }
    else if (i < 2 * per)   { src = k; t = 1; }
    else                    { src = v; t = 2; }
    float4 f = src[i - t * per];
    u16x4 o; o.x = f2bf(f.x); o.y = f2bf(f.y); o.z = f2bf(f.z); o.w = f2bf(f.w);
    out[i] = o;
}

// W [k][n] fp32 -> Wt [n][k] bf16 (per weight z)
__global__ __launch_bounds__(256) void cvt_w(const float* __restrict__ Wq,
                                             const float* __restrict__ Wk,
                                             const float* __restrict__ Wv,
                                             const float* __restrict__ Wo,
                                             unsigned short* __restrict__ wt) {
    __shared__ float tile[64][65];
    const float* W = (blockIdx.z == 0) ? Wq : (blockIdx.z == 1) ? Wk : (blockIdx.z == 2) ? Wv : Wo;
    unsigned short* out = wt + (size_t)blockIdx.z * HIDDEN * HIDDEN;
    int kb = blockIdx.x * 64, nb = blockIdx.y * 64;
    int t = threadIdx.x;
    #pragma unroll
    for (int i = 0; i < 16; i++) {
        int idx = i * 256 + t; int r = idx >> 6, c = idx & 63;
        tile[r][c] = W[(size_t)(kb + r) * HIDDEN + nb + c];
    }
    __syncthreads();
    #pragma unroll
    for (int i = 0; i < 16; i++) {
        int idx = i * 256 + t; int n = idx >> 6, kk = idx & 63;
        out[(size_t)(nb + n) * HIDDEN + kb + kk] = f2bf(tile[kk][n]);
    }
}

__global__ __launch_bounds__(256) void combine_bias(const float4* __restrict__ b,
                                                    const float4* __restrict__ m,
                                                    float4* __restrict__ o) {
    int i = blockIdx.x * 256 + threadIdx.x;   // grid = 2*2048*2048/4/256
    float4 x = b[i], y = m[i];
    o[i] = make_float4(x.x + y.x, x.y + y.y, x.z + y.z, x.w + y.w);
}

// ---------------- 128x128 bf16 MFMA GEMM core ----------------
// X [M][1024] bf16 row-major, Wt [N][1024] bf16 row-major (i.e. W^T).
// acc[rt][ct] = 16x16 C tiles of the wave's 64x64 quadrant.
__device__ __forceinline__ void gemm_core_128(const unsigned short* __restrict__ X,
                                              const unsigned short* __restrict__ Wt,
                                              unsigned short* smem,
                                              int mbase, int nbase, f32x4 acc[4][4]) {
    const int tid = threadIdx.x, w = tid >> 6, ln = tid & 63;
    const int qr = (w >> 1) * 64, qc = (w & 1) * 64;
    const int g = ln >> 4, c16 = ln & 15;
    #pragma unroll
    for (int rt = 0; rt < 4; rt++)
        #pragma unroll
        for (int ct = 0; ct < 4; ct++) acc[rt][ct] = (f32x4){0.f, 0.f, 0.f, 0.f};

    for (int kk = 0; kk < HIDDEN; kk += 64) {
        __syncthreads();   // previous tile's LDS reads done
        #pragma unroll
        for (int pass = 0; pass < 4; pass++) {
            int L = pass * 256 + tid;
            int r = L >> 3, c = (L & 7) ^ (r & 7);              // XOR swizzle
            gload16(X  + (size_t)(mbase + r) * HIDDEN + kk + c * 8,
                    smem + (size_t)(pass * 256 + w * 64) * 8);
            gload16(Wt + (size_t)(nbase + r) * HIDDEN + kk + c * 8,
                    smem + 8192 + (size_t)(pass * 256 + w * 64) * 8);
        }
        __syncthreads();   // drain global_load_lds
        #pragma unroll
        for (int ks = 0; ks < 2; ks++) {
            bf16x8 af[4], bfr[4];
            #pragma unroll
            for (int rt = 0; rt < 4; rt++) {
                int r = qr + rt * 16 + c16;
                int ch = (g + ks * 4) ^ (r & 7);
                af[rt] = *(const bf16x8*)(smem + (size_t)(r * 8 + ch) * 8);
            }
            #pragma unroll
            for (int ct = 0; ct < 4; ct++) {
                int n = qc + ct * 16 + c16;
                int ch = (g + ks * 4) ^ (n & 7);
                bfr[ct] = *(const bf16x8*)(smem + 8192 + (size_t)(n * 8 + ch) * 8);
            }
            #pragma unroll
            for (int rt = 0; rt < 4; rt++)
                #pragma unroll
                for (int ct = 0; ct < 4; ct++)
                    acc[rt][ct] = __builtin_amdgcn_mfma_f32_16x16x32_bf16(af[rt], bfr[ct], acc[rt][ct], 0, 0, 0);
        }
    }
    __syncthreads();   // LDS free for epilogue reuse
}

// ---------------- projections: q->qh(scaled), k->kh, v->vt ----------------
__global__ __launch_bounds__(256, 2) void proj_gemm(const unsigned short* __restrict__ Xall,
                                                    const unsigned short* __restrict__ Wtall,
                                                    const float* __restrict__ bq,
                                                    const float* __restrict__ bk,
                                                    const float* __restrict__ bv,
                                                    unsigned short* __restrict__ qh,
                                                    unsigned short* __restrict__ kh,
                                                    unsigned short* __restrict__ vt) {
    __shared__ __align__(16) unsigned short smem[17408];   // 32KB staging / 34.8KB epilogue
    const int z = blockIdx.z;
    const unsigned short* X  = Xall  + (size_t)z * MTOT * HIDDEN;
    const unsigned short* Wt = Wtall + (size_t)z * HIDDEN * HIDDEN;
    const float* bias = (z == 0) ? bq : (z == 1) ? bk : bv;
    const int mbase = blockIdx.x * 128, nbase = blockIdx.y * 128;
    const int tid = threadIdx.x, w = tid >> 6, ln = tid & 63;
    const int qr = (w >> 1) * 64, qc = (w & 1) * 64;
    const int g = ln >> 4, c16 = ln & 15;

    f32x4 acc[4][4];
    gemm_core_128(X, Wt, smem, mbase, nbase, acc);

    const float scale = (z == 0) ? 0.125f : 1.0f;   // dk^-0.5 folded into qh
    float bias_v[4];
    #pragma unroll
    for (int ct = 0; ct < 4; ct++) bias_v[ct] = bias[nbase + qc + ct * 16 + c16];

    unsigned short* eld = smem + w * 4352;   // 64x68 per wave
    #pragma unroll
    for (int rt = 0; rt < 4; rt++)
        #pragma unroll
        for (int ct = 0; ct < 4; ct++)
            #pragma unroll
            for (int r4 = 0; r4 < 4; r4++) {
                int row_l = rt * 16 + g * 4 + r4;    // pos dim (local)
                int col_l = ct * 16 + c16;           // n dim (local)
                float val = (acc[rt][ct][r4] + bias_v[ct]) * scale;
                if (z == 2) eld[col_l * 68 + row_l] = f2bf(val);  // vt: [d][pos]
                else        eld[row_l * 68 + col_l] = f2bf(val);  // qh/kh: [pos][d]
            }
    __syncthreads();

    const int b = mbase >> 11;
    const int pos0 = (mbase & 2047) + qr;
    if (z < 2) {
        unsigned short* dst = (z == 0) ? qh : kh;
        const int h = (nbase + qc) >> 6;   // constant per wave
        #pragma unroll 4
        for (int i = 0; i < 64; i++)
            dst[((size_t)(b * NHEADS + h) * SEQ + pos0 + i) * DKH + ln] = eld[i * 68 + ln];
    } else {
        #pragma unroll 4
        for (int i = 0; i < 64; i++) {
            int dg = nbase + qc + i;
            int h = dg >> 6, d = dg & 63;
            vt[((size_t)(b * NHEADS + h) * DKH + d) * SEQ + pos0 + ln] = eld[i * 68 + ln];
        }
    }
}

// ---------------- flash attention ----------------
// qh,kh: [BH][SEQ][DKH] bf16 (qh pre-scaled); vt: [BH][DKH][SEQ] bf16
// biasc: [B][SEQ][SEQ] fp32; ctx out: [B*SEQ][HIDDEN] bf16
__global__ __launch_bounds__(256) void attn(const unsigned short* __restrict__ qh,
                                            const unsigned short* __restrict__ kh,
                                            const unsigned short* __restrict__ vt,
                                            const float* __restrict__ biasc,
                                            unsigned short* __restrict__ ctx) {
    __shared__ __align__(16) unsigned short lds_p[4][16][72];
    const int tid = threadIdx.x, w = tid >> 6, ln = tid & 63;
    const int g = ln >> 4, c16 = ln & 15;
    const int qt = blockIdx.x, bh = blockIdx.y;
    const int b = bh >> 4, h = bh & 15;
    const int qbase = qt * 64;

    // Q A-fragments (persistent): row = qbase + w*16 + c16, k = ks*32 + g*8 + j
    const unsigned short* qptr = qh + ((size_t)bh * SEQ + qbase + w * 16 + c16) * DKH;
    bf16x8 aq0 = *(const bf16x8*)(qptr + g * 8);
    bf16x8 aq1 = *(const bf16x8*)(qptr + 32 + g * 8);

    f32x4 accv[4];
    #pragma unroll
    for (int dt = 0; dt < 4; dt++) accv[dt] = (f32x4){0.f, 0.f, 0.f, 0.f};
    float m_run[4], l_run[4];
    #pragma unroll
    for (int r = 0; r < 4; r++) { m_run[r] = -1e30f; l_run[r] = 0.f; }

    const float* brow[4];
    #pragma unroll
    for (int r = 0; r < 4; r++)
        brow[r] = biasc + ((size_t)b * SEQ + qbase + w * 16 + g * 4 + r) * SEQ;

    const unsigned short* kbp = kh + (size_t)bh * SEQ * DKH;
    const unsigned short* vbp = vt + (size_t)bh * DKH * SEQ;

    for (int kt = 0; kt < SEQ; kt += 64) {
        // S = (Q*scale) K^T  (scale folded into qh)
        f32x4 s[4];
        #pragma unroll
        for (int c = 0; c < 4; c++) s[c] = (f32x4){0.f, 0.f, 0.f, 0.f};
        #pragma unroll
        for (int c = 0; c < 4; c++) {
            const unsigned short* kp = kbp + (size_t)(kt + c * 16 + c16) * DKH + g * 8;
            bf16x8 bk0 = *(const bf16x8*)kp;
            bf16x8 bk1 = *(const bf16x8*)(kp + 32);
            s[c] = __builtin_amdgcn_mfma_f32_16x16x32_bf16(aq0, bk0, s[c], 0, 0, 0);
            s[c] = __builtin_amdgcn_mfma_f32_16x16x32_bf16(aq1, bk1, s[c], 0, 0, 0);
        }
        // + bias(+mask)
        #pragma unroll
        for (int c = 0; c < 4; c++)
            #pragma unroll
            for (int r = 0; r < 4; r++)
                s[c][r] += brow[r][kt + c * 16 + c16];
        // row max (rows live in 16-lane groups: row = g*4+r, cols = lane&15 across 4 c-tiles)
        float mx[4];
        #pragma unroll
        for (int r = 0; r < 4; r++)
            mx[r] = fmaxf(fmaxf(s[0][r], s[1][r]), fmaxf(s[2][r], s[3][r]));
        #pragma unroll
        for (int off = 1; off < 16; off <<= 1)
            #pragma unroll
            for (int r = 0; r < 4; r++)
                mx[r] = fmaxf(mx[r], __shfl_xor(mx[r], off));
        float alpha[4];
        #pragma unroll
        for (int r = 0; r < 4; r++) {
            float mn = fmaxf(m_run[r], mx[r]);
            alpha[r] = __expf(m_run[r] - mn);
            m_run[r] = mn;
        }
        // P = exp(S - m)
        #pragma unroll
        for (int c = 0; c < 4; c++)
            #pragma unroll
            for (int r = 0; r < 4; r++)
                s[c][r] = __expf(s[c][r] - m_run[r]);
        float rs[4];
        #pragma unroll
        for (int r = 0; r < 4; r++) rs[r] = s[0][r] + s[1][r] + s[2][r] + s[3][r];
        #pragma unroll
        for (int off = 1; off < 16; off <<= 1)
            #pragma unroll
            for (int r = 0; r < 4; r++) rs[r] += __shfl_xor(rs[r], off);
        #pragma unroll
        for (int r = 0; r < 4; r++) l_run[r] = l_run[r] * alpha[r] + rs[r];
        #pragma unroll
        for (int dt = 0; dt < 4; dt++)
            #pragma unroll
            for (int r = 0; r < 4; r++) accv[dt][r] *= alpha[r];
        // P: C-layout -> LDS -> A-operand layout
        #pragma unroll
        for (int c = 0; c < 4; c++)
            #pragma unroll
            for (int r = 0; r < 4; r++)
                lds_p[w][g * 4 + r][c * 16 + c16] = f2bf(s[c][r]);
        __syncthreads();
        bf16x8 ap0 = *(const bf16x8*)&lds_p[w][c16][g * 8];
        bf16x8 ap1 = *(const bf16x8*)&lds_p[w][c16][32 + g * 8];
        #pragma unroll
        for (int dt = 0; dt < 4; dt++) {
            const unsigned short* vp = vbp + (size_t)(dt * 16 + c16) * SEQ + kt + g * 8;
            bf16x8 bv0 = *(const bf16x8*)vp;
            bf16x8 bv1 = *(const bf16x8*)(vp + 32);
            accv[dt] = __builtin_amdgcn_mfma_f32_16x16x32_bf16(ap0, bv0, accv[dt], 0, 0, 0);
            accv[dt] = __builtin_amdgcn_mfma_f32_16x16x32_bf16(ap1, bv1, accv[dt], 0, 0, 0);
        }
        __syncthreads();
    }
    float inv[4];
    #pragma unroll
    for (int r = 0; r < 4; r++) inv[r] = 1.0f / l_run[r];
    #pragma unroll
    for (int dt = 0; dt < 4; dt++)
        #pragma unroll
        for (int r = 0; r < 4; r++)
            ctx[((size_t)(b * SEQ) + qbase + w * 16 + g * 4 + r) * HIDDEN + h * DKH + dt * 16 + c16]
                = f2bf(accv[dt][r] * inv[r]);
}

// ---------------- output projection ----------------
__global__ __launch_bounds__(256, 2) void outproj(const unsigned short* __restrict__ X,
                                                  const unsigned short* __restrict__ Wt,
                                                  const float* __restrict__ bo,
                                                  float* __restrict__ out) {
    __shared__ __align__(16) unsigned short smem[16384];
    const int mbase = blockIdx.x * 128, nbase = blockIdx.y * 128;
    const int tid = threadIdx.x, w = tid >> 6, ln = tid & 63;
    const int qr = (w >> 1) * 64, qc = (w & 1) * 64;
    const int g = ln >> 4, c16 = ln & 15;

    f32x4 acc[4][4];
    gemm_core_128(X, Wt, smem, mbase, nbase, acc);

    float bo_v[4];
    #pragma unroll
    for (int ct = 0; ct < 4; ct++) bo_v[ct] = bo[nbase + qc + ct * 16 + c16];
    #pragma unroll
    for (int rt = 0; rt < 4; rt++)
        #pragma unroll
        for (int ct = 0; ct < 4; ct++)
            #pragma unroll
            for (int r4 = 0; r4 < 4; r4++)
                out[(size_t)(mbase + qr + rt * 16 + g * 4 + r4) * HIDDEN + nbase + qc + ct * 16 + c16]
                    = acc[rt][ct][r4] + bo_v[ct];
}

// ---------------- launch ----------------
extern "C" void kernel_launch(void* const* d_in, const int* in_sizes, int n_in,
                              void* d_out, int out_size, void* d_ws, size_t ws_size,
                              hipStream_t stream) {
    const float* q    = (const float*)d_in[0];
    const float* k    = (const float*)d_in[1];
    const float* v    = (const float*)d_in[2];
    const float* bias = (const float*)d_in[3];
    const float* mask = (const float*)d_in[4];
    const float* Wq   = (const float*)d_in[5];
    const float* bq   = (const float*)d_in[6];
    const float* Wk   = (const float*)d_in[7];
    const float* bk   = (const float*)d_in[8];
    const float* Wv   = (const float*)d_in[9];
    const float* bv   = (const float*)d_in[10];
    const float* Wo   = (const float*)d_in[11];
    const float* bo   = (const float*)d_in[12];

    char* ws = (char*)d_ws;
    unsigned short* qkv_bf = (unsigned short*)(ws);              // 3 x 4096x1024 bf16
    unsigned short* wt     = (unsigned short*)(ws + 25165824);   // 4 x 1024x1024 bf16 (transposed)
    unsigned short* qh     = (unsigned short*)(ws + 33554432);   // [32][2048][64]
    unsigned short* kh     = (unsigned short*)(ws + 41943040);   // [32][2048][64]
    unsigned short* vt     = (unsigned short*)(ws + 50331648);   // [32][64][2048]
    unsigned short* ctx    = (unsigned short*)(ws + 58720256);   // [4096][1024]
    float*          biasc  = (float*)(ws + 67108864);            // [2][2048][2048] fp32
    // total ws use: 100,663,296 bytes

    cvt_qkv<<<12288, 256, 0, stream>>>((const float4*)q, (const float4*)k, (const float4*)v,
                                       (u16x4*)qkv_bf);
    cvt_w<<<dim3(16, 16, 4), 256, 0, stream>>>(Wq, Wk, Wv, Wo, wt);
    combine_bias<<<8192, 256, 0, stream>>>((const float4*)bias, (const float4*)mask,
                                           (float4*)biasc);
    proj_gemm<<<dim3(32, 8, 3), 256, 0, stream>>>(qkv_bf, wt, bq, bk, bv, qh, kh, vt);
    attn<<<dim3(32, 32), 256, 0, stream>>>(qh, kh, vt, biasc, ctx);
    outproj<<<dim3(32, 8), 256, 0, stream>>>(ctx, wt + (size_t)3 * HIDDEN * HIDDEN, bo,
                                             (float*)d_out);
}